// Round 7
// baseline (105.875 us; speedup 1.0000x reference)
//
#include <hip/hip_runtime.h>
#include <hip/hip_bf16.h>
#include <math.h>

// Problem constants (fixed by reference setup_inputs)
#define DH 48
#define DW 48
#define DT 48
#define DC 32
#define NPOS (DH * DW * DT)

// Position tile per block and its halo
#define TH 2
#define TW 4
#define TT 4
#define LH (TH + 2)                 // 4
#define LW (TW + 2)                 // 6
#define LT (TT + 2)                 // 6
#define NLINES (LH * LW * LT)       // 144 k-lines of 128 B
#define NF4 (NLINES * 8)            // 1152 float4 staging slots
#define NTHREADS (TH * TW * TT * 8) // 256 (32 positions x 8 lanes)

// Block = 2x4x4 position tile, 8 lanes per position (4 channels each).
// k halo staged in LDS (18.4 KB) with branch-free clamped loads; validity
// handled as 0/1 score scales after the butterfly (zero-pad semantics).
__global__ __launch_bounds__(NTHREADS) void cotr_natt_kernel(
    const float* __restrict__ q,
    const float* __restrict__ k,
    float* __restrict__ out)
{
    __shared__ float kl[NLINES * DC]; // 18432 B

    // Tile origin
    const int bt = blockIdx.x % (DT / TT);
    const int bw = (blockIdx.x / (DT / TT)) % (DW / TW);
    const int bh = blockIdx.x / ((DT / TT) * (DW / TW));
    const int h0 = bh * TH, w0 = bw * TW, t0 = bt * TT;

    const int tid = threadIdx.x;
    const int p = tid >> 3;   // local position 0..31
    const int sub = tid & 7;  // channel quad 0..7
    const int lh = p >> 4;            // p / (TW*TT)
    const int lw = (p >> 2) & 3;
    const int lt = p & 3;
    const int h = h0 + lh, w = w0 + lw, t = t0 + lt;
    const int idx = (h * DW + w) * DT + t;

    // q load first (independent of staging; overlaps)
    const float4 qv =
        *reinterpret_cast<const float4*>(q + (size_t)idx * DC + sub * 4);

    // ---- stage 144 halo lines, branch-free clamped addresses ----
    float4 tmp[5];
#pragma unroll
    for (int i = 0; i < 5; ++i) {
        const int s = i * NTHREADS + tid;
        if (s < NF4) {
            const int line = s >> 3, c4 = s & 7;
            const int llt = line % LT;
            const int llw = (line / LT) % LW;
            const int llh = line / (LT * LW);
            const int hh = min(max(h0 + llh - 1, 0), DH - 1);
            const int ww = min(max(w0 + llw - 1, 0), DW - 1);
            const int tt = min(max(t0 + llt - 1, 0), DT - 1);
            tmp[i] = *reinterpret_cast<const float4*>(
                k + ((size_t)(hh * DW + ww) * DT + tt) * DC + c4 * 4);
        }
    }
#pragma unroll
    for (int i = 0; i < 5; ++i) {
        const int s = i * NTHREADS + tid;
        if (s < NF4)
            *reinterpret_cast<float4*>(&kl[s * 4]) = tmp[i];
    }
    __syncthreads();

    // ---- 27 partial dots from LDS (conflict-free ds_read_b128) ----
    float part[27];
#pragma unroll
    for (int a = 0; a < 3; ++a) {
#pragma unroll
        for (int b = 0; b < 3; ++b) {
#pragma unroll
            for (int c = 0; c < 3; ++c) {
                const int line = ((lh + a) * LW + (lw + b)) * LT + (lt + c);
                const float4 kv = *reinterpret_cast<const float4*>(
                    &kl[line * DC + sub * 4]);
                part[(a * 3 + b) * 3 + c] =
                    fmaf(qv.x, kv.x,
                    fmaf(qv.y, kv.y,
                    fmaf(qv.z, kv.z, qv.w * kv.w)));
            }
        }
    }

    // Validity scales (zero-pad semantics: invalid neighbor => score 0)
    float as_[3], bs_[3], cs_[3];
#pragma unroll
    for (int u = 0; u < 3; ++u) {
        as_[u] = ((unsigned)(h + u - 1) < DH) ? 1.0f : 0.0f;
        bs_[u] = ((unsigned)(w + u - 1) < DW) ? 1.0f : 0.0f;
        cs_[u] = ((unsigned)(t + u - 1) < DT) ? 1.0f : 0.0f;
    }

    // Butterfly-reduce across the 8-lane channel group, then scale.
    float m = -INFINITY;
#pragma unroll
    for (int j = 0; j < 27; ++j) {
        float v = part[j];
        v += __shfl_xor(v, 1, 64);
        v += __shfl_xor(v, 2, 64);
        v += __shfl_xor(v, 4, 64);
        v *= as_[j / 9] * bs_[(j / 3) % 3] * cs_[j % 3];
        part[j] = v;
        m = fmaxf(m, v);
    }

    // Softmax over 27 + displacement-weighted sum (j = a*9 + b*3 + c).
    float sum = 0.0f;
    float oh = 0.0f, ow = 0.0f, ot = 0.0f;
#pragma unroll
    for (int j = 0; j < 27; ++j) {
        const float e = __expf(part[j] - m);
        sum += e;
        const float da = (float)(j / 9 - 1);
        const float db = (float)((j / 3) % 3 - 1);
        const float dc = (float)(j % 3 - 1);
        oh = fmaf(e, da, oh);
        ow = fmaf(e, db, ow);
        ot = fmaf(e, dc, ot);
    }
    const float inv = 1.0f / sum;

    // Output layout [B, 3, H, W, T]; lanes 0/1/2 of each group write dh/dw/dt.
    if (sub == 0)      out[0 * NPOS + idx] = oh * inv;
    else if (sub == 1) out[1 * NPOS + idx] = ow * inv;
    else if (sub == 2) out[2 * NPOS + idx] = ot * inv;
}

extern "C" void kernel_launch(void* const* d_in, const int* in_sizes, int n_in,
                              void* d_out, int out_size, void* d_ws, size_t ws_size,
                              hipStream_t stream) {
    const float* q = reinterpret_cast<const float*>(d_in[0]);
    const float* k = reinterpret_cast<const float*>(d_in[1]);
    float* out = reinterpret_cast<float*>(d_out);

    const int blocks = (DH / TH) * (DW / TW) * (DT / TT); // 24*12*12 = 3456
    cotr_natt_kernel<<<blocks, NTHREADS, 0, stream>>>(q, k, out);
}

// Round 8
// 86.346 us; speedup vs baseline: 1.2262x; 1.2262x over previous
//
#include <hip/hip_runtime.h>
#include <hip/hip_bf16.h>
#include <math.h>

// Problem constants (fixed by reference setup_inputs)
#define DH 48
#define DW 48
#define DT 48
#define DC 32
#define NPOS (DH * DW * DT)

// Position tile per block and its halo
#define TH 2
#define TW 4
#define TT 4
#define LH (TH + 2)                 // 4
#define LW (TW + 2)                 // 6
#define LT (TT + 2)                 // 6
#define NLINES (LH * LW * LT)       // 144 k-lines of 128 B
#define NF4 (NLINES * 8)            // 1152 float4 staging slots
#define NTHREADS 256                // 32 positions x 8 lanes

typedef __attribute__((address_space(3))) unsigned int lds_u32_t;
typedef const __attribute__((address_space(1))) unsigned int glb_u32_t;

// Block = 2x4x4 position tile, 8 lanes per position (4 channels each).
// k halo staged in LDS via global_load_lds DMA (no staging VGPRs, no spill);
// validity = 0/1 score scales after the butterfly (zero-pad semantics).
// __launch_bounds__(256,4): 128-VGPR cap so part[27] stays in registers.
__global__ __launch_bounds__(NTHREADS, 4) void cotr_natt_kernel(
    const float* __restrict__ q,
    const float* __restrict__ k,
    float* __restrict__ out)
{
    __shared__ __align__(16) float kl[NF4 * 4]; // 18432 B

    // Tile origin
    const int bt = blockIdx.x % (DT / TT);
    const int bw = (blockIdx.x / (DT / TT)) % (DW / TW);
    const int bh = blockIdx.x / ((DT / TT) * (DW / TW));
    const int h0 = bh * TH, w0 = bw * TW, t0 = bt * TT;

    const int tid = threadIdx.x;

    // ---- stage 144 halo lines straight into LDS (async DMA) ----
    // slot s -> LDS byte s*16 (linear, lane-contiguous = HW pattern);
    // global source per-lane with clamped halo coords (always in-bounds).
#pragma unroll
    for (int i = 0; i < 5; ++i) {
        const int s = i * NTHREADS + tid;
        if (s < NF4) {
            const int line = s >> 3, c4 = s & 7;
            const int llt = line % LT;
            const int llw = (line / LT) % LW;
            const int llh = line / (LT * LW);
            const int hh = min(max(h0 + llh - 1, 0), DH - 1);
            const int ww = min(max(w0 + llw - 1, 0), DW - 1);
            const int tt = min(max(t0 + llt - 1, 0), DT - 1);
            const float* gp =
                k + ((size_t)(hh * DW + ww) * DT + tt) * DC + c4 * 4;
            __builtin_amdgcn_global_load_lds((glb_u32_t*)gp,
                                             (lds_u32_t*)&kl[s * 4], 16, 0, 0);
        }
    }

    // position/channel decomposition
    const int p = tid >> 3;   // local position 0..31
    const int sub = tid & 7;  // channel quad 0..7
    const int lh = p >> 4;
    const int lw = (p >> 2) & 3;
    const int lt = p & 3;
    const int h = h0 + lh, w = w0 + lw, t = t0 + lt;
    const int idx = (h * DW + w) * DT + t;

    // q load overlaps the DMA; drained together by the barrier below
    const float4 qv =
        *reinterpret_cast<const float4*>(q + (size_t)idx * DC + sub * 4);

    __syncthreads();

    // ---- 27 partial dots from LDS (contiguous ds_read_b128) ----
    float part[27];
#pragma unroll
    for (int a = 0; a < 3; ++a) {
#pragma unroll
        for (int b = 0; b < 3; ++b) {
#pragma unroll
            for (int c = 0; c < 3; ++c) {
                const int line = ((lh + a) * LW + (lw + b)) * LT + (lt + c);
                const float4 kv = *reinterpret_cast<const float4*>(
                    &kl[line * DC + sub * 4]);
                part[(a * 3 + b) * 3 + c] =
                    fmaf(qv.x, kv.x,
                    fmaf(qv.y, kv.y,
                    fmaf(qv.z, kv.z, qv.w * kv.w)));
            }
        }
    }

    // Validity scales (zero-pad semantics: invalid neighbor => score 0)
    float as_[3], bs_[3], cs_[3];
#pragma unroll
    for (int u = 0; u < 3; ++u) {
        as_[u] = ((unsigned)(h + u - 1) < DH) ? 1.0f : 0.0f;
        bs_[u] = ((unsigned)(w + u - 1) < DW) ? 1.0f : 0.0f;
        cs_[u] = ((unsigned)(t + u - 1) < DT) ? 1.0f : 0.0f;
    }

    // Butterfly-reduce across the 8-lane channel group, then scale.
    float m = -INFINITY;
#pragma unroll
    for (int j = 0; j < 27; ++j) {
        float v = part[j];
        v += __shfl_xor(v, 1, 64);
        v += __shfl_xor(v, 2, 64);
        v += __shfl_xor(v, 4, 64);
        v *= as_[j / 9] * bs_[(j / 3) % 3] * cs_[j % 3];
        part[j] = v;
        m = fmaxf(m, v);
    }

    // Softmax over 27 + displacement-weighted sum (j = a*9 + b*3 + c).
    float sum = 0.0f;
    float oh = 0.0f, ow = 0.0f, ot = 0.0f;
#pragma unroll
    for (int j = 0; j < 27; ++j) {
        const float e = __expf(part[j] - m);
        sum += e;
        const float da = (float)(j / 9 - 1);
        const float db = (float)((j / 3) % 3 - 1);
        const float dc = (float)(j % 3 - 1);
        oh = fmaf(e, da, oh);
        ow = fmaf(e, db, ow);
        ot = fmaf(e, dc, ot);
    }
    const float inv = 1.0f / sum;

    // Output layout [B, 3, H, W, T]; lanes 0/1/2 of each group write dh/dw/dt.
    if (sub == 0)      out[0 * NPOS + idx] = oh * inv;
    else if (sub == 1) out[1 * NPOS + idx] = ow * inv;
    else if (sub == 2) out[2 * NPOS + idx] = ot * inv;
}

extern "C" void kernel_launch(void* const* d_in, const int* in_sizes, int n_in,
                              void* d_out, int out_size, void* d_ws, size_t ws_size,
                              hipStream_t stream) {
    const float* q = reinterpret_cast<const float*>(d_in[0]);
    const float* k = reinterpret_cast<const float*>(d_in[1]);
    float* out = reinterpret_cast<float*>(d_out);

    const int blocks = (DH / TH) * (DW / TW) * (DT / TT); // 24*12*12 = 3456
    cotr_natt_kernel<<<blocks, NTHREADS, 0, stream>>>(q, k, out);
}

// Round 10
// 78.560 us; speedup vs baseline: 1.3477x; 1.0991x over previous
//
#include <hip/hip_runtime.h>
#include <hip/hip_bf16.h>
#include <math.h>

// Problem constants (fixed by reference setup_inputs)
#define DH 48
#define DW 48
#define DT 48
#define DC 32
#define NPOS (DH * DW * DT)

// Position tile per block and its halo
#define TH 4
#define TW 4
#define TT 4
#define LH (TH + 2)                 // 6
#define LW (TW + 2)                 // 6
#define LT (TT + 2)                 // 6
#define NLINES (LH * LW * LT)       // 216 k-lines of 128 B
#define NF4 (NLINES * 8)            // 1728 float4 staging slots
#define NTHREADS 256                // 64 positions x 4 lanes

typedef __attribute__((address_space(3))) unsigned int lds_u32_t;
typedef const __attribute__((address_space(1))) unsigned int glb_u32_t;

// quad_perm DPP add: v += lane-shuffled v within each 4-lane quad (VALU pipe,
// zero LDS-pipe cost). CTRL: 0xB1 = xor1 ([1,0,3,2]), 0x4E = xor2 ([2,3,0,1]).
template <int CTRL>
__device__ __forceinline__ float qperm_add(float v) {
    const int s = __builtin_amdgcn_update_dpp(
        0, __float_as_int(v), CTRL, 0xF, 0xF, true);
    return v + __int_as_float(s);
}

// Block = 4x4x4 position tile, 4 lanes/position (8 channels each).
// Halo staged via global_load_lds DMA; butterfly via DPP quad_perm;
// validity = 0/1 score scales (zero-pad semantics).
__global__ __launch_bounds__(NTHREADS, 5) void cotr_natt_kernel(
    const float* __restrict__ q,
    const float* __restrict__ k,
    float* __restrict__ out)
{
    __shared__ __align__(16) float kl[NF4 * 4]; // 27648 B

    // Tile origin (12x12x12 blocks)
    const int bt = blockIdx.x % (DT / TT);
    const int bw = (blockIdx.x / (DT / TT)) % (DW / TW);
    const int bh = blockIdx.x / ((DT / TT) * (DW / TW));
    const int h0 = bh * TH, w0 = bw * TW, t0 = bt * TT;

    const int tid = threadIdx.x;

    // ---- stage 216 halo lines straight into LDS (async DMA) ----
    // LDS dst linear (slot*16, lane-contiguous = HW pattern); global src
    // per-lane with clamped halo coords (always in-bounds, zeroed later).
#pragma unroll
    for (int i = 0; i < 7; ++i) {
        const int s = i * NTHREADS + tid;
        if (s < NF4) {
            const int line = s >> 3, c4 = s & 7;
            const int llt = line % LT;
            const int lhw = line / LT;
            const int llw = lhw % LW;
            const int llh = lhw / LW;
            const int hh = min(max(h0 + llh - 1, 0), DH - 1);
            const int ww = min(max(w0 + llw - 1, 0), DW - 1);
            const int tt = min(max(t0 + llt - 1, 0), DT - 1);
            const float* gp =
                k + ((size_t)(hh * DW + ww) * DT + tt) * DC + c4 * 4;
            __builtin_amdgcn_global_load_lds((glb_u32_t*)gp,
                                             (lds_u32_t*)&kl[s * 4], 16, 0, 0);
        }
    }

    // position/channel decomposition: quad = one position
    const int p = tid >> 2;    // local position 0..63
    const int sub = tid & 3;   // channel octet 0..3
    const int lt = p & 3;
    const int lw = (p >> 2) & 3;
    const int lh = p >> 4;
    const int h = h0 + lh, w = w0 + lw, t = t0 + lt;
    const int idx = (h * DW + w) * DT + t;

    // q channels [sub*8, sub*8+8): 2 float4 (overlaps the DMA)
    const float4* qp = reinterpret_cast<const float4*>(q + (size_t)idx * DC);
    const float4 qa = qp[sub * 2];
    const float4 qb = qp[sub * 2 + 1];

    __syncthreads();

    // ---- 27 partial dots from LDS (2 ds_read_b128 each, conflict-free) ----
    float part[27];
#pragma unroll
    for (int a = 0; a < 3; ++a) {
#pragma unroll
        for (int b = 0; b < 3; ++b) {
#pragma unroll
            for (int c = 0; c < 3; ++c) {
                const int line = ((lh + a) * LW + (lw + b)) * LT + (lt + c);
                const float4* kp =
                    reinterpret_cast<const float4*>(&kl[line * DC]);
                const float4 ka = kp[sub * 2];
                const float4 kb = kp[sub * 2 + 1];
                part[(a * 3 + b) * 3 + c] =
                    fmaf(qa.x, ka.x,
                    fmaf(qa.y, ka.y,
                    fmaf(qa.z, ka.z,
                    fmaf(qa.w, ka.w,
                    fmaf(qb.x, kb.x,
                    fmaf(qb.y, kb.y,
                    fmaf(qb.z, kb.z, qb.w * kb.w)))))));
            }
        }
    }

    // Validity scales (zero-pad semantics: invalid neighbor => score 0)
    float as_[3], bs_[3], cs_[3];
#pragma unroll
    for (int u = 0; u < 3; ++u) {
        as_[u] = ((unsigned)(h + u - 1) < DH) ? 1.0f : 0.0f;
        bs_[u] = ((unsigned)(w + u - 1) < DW) ? 1.0f : 0.0f;
        cs_[u] = ((unsigned)(t + u - 1) < DT) ? 1.0f : 0.0f;
    }

    // 2-round DPP butterfly within the quad (all 4 lanes get full scores),
    // then validity scale + running max.
    float m = -INFINITY;
#pragma unroll
    for (int j = 0; j < 27; ++j) {
        float v = part[j];
        v = qperm_add<0xB1>(v);  // xor1
        v = qperm_add<0x4E>(v);  // xor2
        v *= as_[j / 9] * bs_[(j / 3) % 3] * cs_[j % 3];
        part[j] = v;
        m = fmaxf(m, v);
    }

    // Softmax over 27 + displacement-weighted sum (j = a*9 + b*3 + c).
    float sum = 0.0f;
    float oh = 0.0f, ow = 0.0f, ot = 0.0f;
#pragma unroll
    for (int j = 0; j < 27; ++j) {
        const float e = __expf(part[j] - m);
        sum += e;
        const float da = (float)(j / 9 - 1);
        const float db = (float)((j / 3) % 3 - 1);
        const float dc = (float)(j % 3 - 1);
        oh = fmaf(e, da, oh);
        ow = fmaf(e, db, ow);
        ot = fmaf(e, dc, ot);
    }
    const float inv = 1.0f / sum;

    // Output layout [B, 3, H, W, T]; lanes 0/1/2 of each quad write dh/dw/dt.
    if (sub == 0)      out[0 * NPOS + idx] = oh * inv;
    else if (sub == 1) out[1 * NPOS + idx] = ow * inv;
    else if (sub == 2) out[2 * NPOS + idx] = ot * inv;
}

extern "C" void kernel_launch(void* const* d_in, const int* in_sizes, int n_in,
                              void* d_out, int out_size, void* d_ws, size_t ws_size,
                              hipStream_t stream) {
    const float* q = reinterpret_cast<const float*>(d_in[0]);
    const float* k = reinterpret_cast<const float*>(d_in[1]);
    float* out = reinterpret_cast<float*>(d_out);

    const int blocks = (DH / TH) * (DW / TW) * (DT / TT); // 12*12*12 = 1728
    cotr_natt_kernel<<<blocks, NTHREADS, 0, stream>>>(q, k, out);
}